// Round 3
// baseline (3911.609 us; speedup 1.0000x reference)
//
#include <hip/hip_runtime.h>
#include <math.h>

#define TT 256
#define HC 128
#define HB 64
#define NL 8

// ---- ws layout (floats) ----
#define WS_WGT 0
#define WS_PB  65536
#define WS_PG  66048
#define WS_GP  66560
#define WS_BP  67584

__device__ __forceinline__ float fast_tanh(float x) {
    float e = __expf(2.f * fabsf(x));
    float r = 1.f - 2.f / (1.f + e);
    return copysignf(r, x);
}
__device__ __forceinline__ float fast_sig(float x) {
    return 1.f / (1.f + __expf(-x));
}

__global__ __launch_bounds__(128)
void tcn_setup(const float* __restrict__ pw_in, const float* __restrict__ gn_g,
               const float* __restrict__ gn_b, float* __restrict__ ws) {
    int i = blockIdx.x;      // layer
    int tid = threadIdx.x;   // 128 threads
    float* WgT = ws + WS_WGT;
    float* Pb  = ws + WS_PB;
    float* Pg  = ws + WS_PG;
    float* Gp  = ws + WS_GP;
    float* Bp  = ws + WS_BP;

    float g = (i == 0) ? 1.f : gn_g[(i - 1) * HC + tid];
    float bb = (i == 0) ? 0.f : gn_b[(i - 1) * HC + tid];
    Gp[i * HC + tid] = g;
    Bp[i * HC + tid] = bb;
    for (int o = 0; o < HB; o++)
        WgT[(i * HC + tid) * HB + o] = pw_in[((size_t)i * HB + o) * HC + tid] * g;

    if (tid < HB) {
        float pb = 0.f, pg = 0.f;
        for (int c = 0; c < HC; c++) {
            float w = pw_in[((size_t)i * HB + tid) * HC + c];
            float gc = (i == 0) ? 1.f : gn_g[(i - 1) * HC + c];
            float bc = (i == 0) ? 0.f : gn_b[(i - 1) * HC + c];
            pb += bc * w;
            pg += gc * w;
        }
        Pb[i * HB + tid] = pb;
        Pg[i * HB + tid] = pg;
    }
}

// Static LDS (floats):
//   halo  [64][68]  4352 : u values for rows with (t&63)>=48 (fp32)
//   sLast [8][128]  1024
//   red   [16], wbuf[64], hbuf[128], qbuf[128]
// total 5712 floats = 22848 B  -> 2 blocks/CU trivially fits
__global__ __launch_bounds__(256, 2)
void tcn_main(const float* __restrict__ x, const float* __restrict__ in_w,
              const float* __restrict__ in_b, const float* __restrict__ dw_w,
              const float* __restrict__ pw_out, const float* __restrict__ skip_w,
              const float* __restrict__ ln_g, const float* __restrict__ ln_b,
              const float* __restrict__ h1_w, const float* __restrict__ h1_b,
              const float* __restrict__ h2_w, const float* __restrict__ h2_b,
              const float* __restrict__ ws, float* __restrict__ out) {
    __shared__ float halo[64 * 68];
    __shared__ float sLast[NL * HC];
    __shared__ float red[16];
    __shared__ float wbuf[64];
    __shared__ float hbuf[128];
    __shared__ float qbuf[128];

    const float* WgT = ws + WS_WGT;
    const float* Pb  = ws + WS_PB;
    const float* Pg  = ws + WS_PG;
    const float* Gp  = ws + WS_GP;
    const float* Bp  = ws + WS_BP;

    const int t = threadIdx.x;     // time index, 0..255
    const int bn = blockIdx.x;     // sample
    const int b = bn >> 7, n = bn & 127;
    const int lane = t & 63;
    const int wv = t >> 6;

    // residual state z[:, t] lives entirely in this thread's registers (fp32)
    float z[HC];

    // ---------- phase 0: input projection  z[c] = x[b,t,n,:] @ in_w + in_b
    {
        const float* xp = x + (((size_t)b * TT + t) * 128 + n) * 16;
        float xr[16];
#pragma unroll
        for (int d = 0; d < 16; d++) xr[d] = xp[d];
#pragma unroll
        for (int c = 0; c < HC; c += 2) {
            float a0 = in_b[c], a1 = in_b[c + 1];
#pragma unroll
            for (int d = 0; d < 16; d++) {
                a0 = fmaf(xr[d], in_w[d * HC + c], a0);
                a1 = fmaf(xr[d], in_w[d * HC + c + 1], a1);
            }
            z[c] = a0;
            z[c + 1] = a1;
        }
    }

    float m_s = 0.f, r_s = 1.f;   // deferred groupnorm scalars

#pragma unroll 1
    for (int L = 0; L < NL; L++) {
        const int dil = 1 << (L & 3);
        const bool lastL = (L == NL - 1);
        const bool active = (!lastL) || (wv == 3);

        // ---------- u-phase: u[o] = r*(z . WgT[:,o]) + Pb[o] - m*r*Pg[o]
        float u[HB];
        if (active) {
            const float* W = WgT + (size_t)L * HC * HB;
#pragma unroll
            for (int o = 0; o < HB; o++) u[o] = 0.f;
#pragma unroll
            for (int c = 0; c < HC; c++) {
                float zr = z[c];
#pragma unroll
                for (int o = 0; o < HB; o++) u[o] = fmaf(zr, W[c * HB + o], u[o]);
            }
            float mr = m_s * r_s;
#pragma unroll
            for (int o = 0; o < HB; o++)
                u[o] = fmaf(r_s, u[o], Pb[L * HB + o] - mr * Pg[L * HB + o]);
            // halo publish: rows with (t&63)>=48 feed next wave's lookback
            if (lane >= 48) {
                int hr = wv * 16 + (lane - 48);
#pragma unroll
                for (int o = 0; o < HB; o++) halo[hr * 68 + o] = u[o];
            }
        }
        __syncthreads();   // B1: halo ready

        // ---------- conv + gating (round-1-verified channel mapping)
        // f[c] uses u[c>>1]; gate[c] uses u[32+(c>>1)]
        float w_[HB];
        if (active) {
            const float* dwl = dw_w + (size_t)L * 128 * 3;
            const int d1 = dil, d2 = 2 * dil;
#pragma unroll
            for (int k = 0; k < 32; k++) {
                float uf = u[k];
                float um1 = __shfl_up(uf, d1);
                float um2 = __shfl_up(uf, d2);
                if (lane < d1) {
                    int tau = t - d1;
                    um1 = (tau < 0) ? 0.f : halo[((tau >> 6) * 16 + (tau & 63) - 48) * 68 + k];
                }
                if (lane < d2) {
                    int tau = t - d2;
                    um2 = (tau < 0) ? 0.f : halo[((tau >> 6) * 16 + (tau & 63) - 48) * 68 + k];
                }
                float f0 = um2 * dwl[(2 * k) * 3 + 0] + um1 * dwl[(2 * k) * 3 + 1] + uf * dwl[(2 * k) * 3 + 2];
                float f1 = um2 * dwl[(2 * k + 1) * 3 + 0] + um1 * dwl[(2 * k + 1) * 3 + 1] + uf * dwl[(2 * k + 1) * 3 + 2];
                w_[2 * k] = fast_tanh(f0);
                w_[2 * k + 1] = fast_tanh(f1);
            }
#pragma unroll
            for (int k = 0; k < 32; k++) {
                float ug = u[32 + k];
                float um1 = __shfl_up(ug, d1);
                float um2 = __shfl_up(ug, d2);
                if (lane < d1) {
                    int tau = t - d1;
                    um1 = (tau < 0) ? 0.f : halo[((tau >> 6) * 16 + (tau & 63) - 48) * 68 + 32 + k];
                }
                if (lane < d2) {
                    int tau = t - d2;
                    um2 = (tau < 0) ? 0.f : halo[((tau >> 6) * 16 + (tau & 63) - 48) * 68 + 32 + k];
                }
                float g0 = um2 * dwl[(64 + 2 * k) * 3 + 0] + um1 * dwl[(64 + 2 * k) * 3 + 1] + ug * dwl[(64 + 2 * k) * 3 + 2];
                float g1 = um2 * dwl[(64 + 2 * k + 1) * 3 + 0] + um1 * dwl[(64 + 2 * k + 1) * 3 + 1] + ug * dwl[(64 + 2 * k + 1) * 3 + 2];
                w_[2 * k] *= fast_sig(g0);
                w_[2 * k + 1] *= fast_sig(g1);
            }
        }

        if (!lastL) {
            // ---------- s-phase: s_feat, residual update (deferred GN), stats
            float s1 = 0.f, s2 = 0.f;
            const float* Po = pw_out + (size_t)L * HC * HB;
            const float mr = m_s * r_s;
            const float* gp = Gp + L * HC;
            const float* bp = Bp + L * HC;
#pragma unroll
            for (int c = 0; c < HC; c += 2) {
                float a0 = 0.f, b0 = 0.f, a1 = 0.f, b1 = 0.f;
#pragma unroll
                for (int cc = 0; cc < 32; cc++) {
                    a0 = fmaf(w_[2 * cc],     Po[c * HB + 2 * cc],           a0);
                    b0 = fmaf(w_[2 * cc + 1], Po[c * HB + 2 * cc + 1],       b0);
                    a1 = fmaf(w_[2 * cc],     Po[(c + 1) * HB + 2 * cc],     a1);
                    b1 = fmaf(w_[2 * cc + 1], Po[(c + 1) * HB + 2 * cc + 1], b1);
                }
                float acc0 = a0 + b0, acc1 = a1 + b1;
                if (t == TT - 1) {
                    sLast[L * HC + c] = acc0;
                    sLast[L * HC + c + 1] = acc1;
                }
                float g0 = gp[c], g1 = gp[c + 1];
                float zn0 = fmaf(z[c],     r_s * g0, (bp[c]     - mr * g0) + acc0);
                float zn1 = fmaf(z[c + 1], r_s * g1, (bp[c + 1] - mr * g1) + acc1);
                z[c] = zn0;
                z[c + 1] = zn1;
                s1 += zn0 + zn1;
                s2 += zn0 * zn0 + zn1 * zn1;
            }
#pragma unroll
            for (int off = 32; off; off >>= 1) {
                s1 += __shfl_xor(s1, off);
                s2 += __shfl_xor(s2, off);
            }
            if (lane == 0) { red[wv * 2] = s1; red[wv * 2 + 1] = s2; }
            __syncthreads();   // B2
            float S1 = red[0] + red[2] + red[4] + red[6];
            float S2 = red[1] + red[3] + red[5] + red[7];
            float mu = S1 * (1.f / 32768.f);
            float var = S2 * (1.f / 32768.f) - mu * mu;
            m_s = mu;
            r_s = rsqrtf(var + 1e-5f);
        } else {
            // last layer: only t==255's gated output matters; parallelize its s-row
            if (t == TT - 1) {
#pragma unroll
                for (int cc = 0; cc < HB; cc++) wbuf[cc] = w_[cc];
            }
            __syncthreads();   // B2: wbuf ready
            if (t < HC) {
                const float* pr = pw_out + ((size_t)(NL - 1) * HC + t) * HB;
                float a = 0.f;
                for (int cc = 0; cc < HB; cc++) a = fmaf(wbuf[cc], pr[cc], a);
                sLast[(NL - 1) * HC + t] = a;
            }
            __syncthreads();   // B3: sLast complete
        }
    }

    // ---------- head: h_last = sum_i skip_w[i] @ sLast[i]; LN; MLP
    float hl = 0.f;
    if (t < HC) {
        for (int i = 0; i < NL; i++) {
            const float4* swr = (const float4*)(skip_w + (((size_t)i * HC) + t) * HC);
            const float* sl = sLast + i * HC;
#pragma unroll 4
            for (int c4 = 0; c4 < 32; c4++) {
                float4 sw = swr[c4];
                hl += sw.x * sl[4 * c4] + sw.y * sl[4 * c4 + 1] + sw.z * sl[4 * c4 + 2] + sw.w * sl[4 * c4 + 3];
            }
        }
        hbuf[t] = hl;
    }
    __syncthreads();
    if (t < 64) {
        float v0 = hbuf[t], v1 = hbuf[t + 64];
        float a = v0 + v1, q = v0 * v0 + v1 * v1;
#pragma unroll
        for (int off = 32; off; off >>= 1) {
            a += __shfl_xor(a, off);
            q += __shfl_xor(q, off);
        }
        if (t == 0) {
            float mu = a * (1.f / 128.f);
            red[0] = mu;
            red[1] = rsqrtf(q * (1.f / 128.f) - mu * mu + 1e-5f);
        }
    }
    __syncthreads();
    {
        float mu = red[0], rs = red[1];
        if (t < HC) hbuf[t] = (hl - mu) * rs * ln_g[t] + ln_b[t];
    }
    __syncthreads();
    if (t < HC) {
        float q = h1_b[t];
        for (int c = 0; c < HC; c++) q = fmaf(hbuf[c], h1_w[c * HC + t], q);
        q = 0.5f * q * (1.f + erff(q * 0.70710678118654752f));
        qbuf[t] = q;
    }
    __syncthreads();
    if (t < 24) {
        float o = h2_b[t];
        for (int c = 0; c < HC; c++) o = fmaf(qbuf[c], h2_w[c * 24 + t], o);
        out[((size_t)b * 24 + t) * 128 + n] = o;
    }
}

extern "C" void kernel_launch(void* const* d_in, const int* in_sizes, int n_in,
                              void* d_out, int out_size, void* d_ws, size_t ws_size,
                              hipStream_t stream) {
    const float* x      = (const float*)d_in[0];
    const float* in_w   = (const float*)d_in[1];
    const float* in_b   = (const float*)d_in[2];
    const float* pw_in  = (const float*)d_in[3];
    const float* dw_w   = (const float*)d_in[4];
    const float* pw_out = (const float*)d_in[5];
    const float* gn_g   = (const float*)d_in[6];
    const float* gn_b   = (const float*)d_in[7];
    const float* skip_w = (const float*)d_in[8];
    const float* ln_g   = (const float*)d_in[9];
    const float* ln_b   = (const float*)d_in[10];
    const float* h1_w   = (const float*)d_in[11];
    const float* h1_b   = (const float*)d_in[12];
    const float* h2_w   = (const float*)d_in[13];
    const float* h2_b   = (const float*)d_in[14];
    float* out = (float*)d_out;
    float* ws  = (float*)d_ws;

    tcn_setup<<<NL, 128, 0, stream>>>(pw_in, gn_g, gn_b, ws);

    tcn_main<<<1024, 256, 0, stream>>>(x, in_w, in_b, dw_w, pw_out, skip_w,
                                       ln_g, ln_b, h1_w, h1_b, h2_w, h2_b, ws, out);
}

// Round 4
// 2452.673 us; speedup vs baseline: 1.5948x; 1.5948x over previous
//
#include <hip/hip_runtime.h>
#include <hip/hip_fp16.h>
#include <math.h>

#define TT 256
#define HC 128
#define HB 64
#define NL 8

// ---- ws layout (floats) ----
#define WS_WGT 0
#define WS_PB  65536
#define WS_PG  66048
#define WS_GP  66560
#define WS_BP  67584

__device__ __forceinline__ float fast_tanh(float x) {
    float e = __expf(2.f * fabsf(x));
    float r = 1.f - 2.f / (1.f + e);
    return copysignf(r, x);
}
__device__ __forceinline__ float fast_sig(float x) {
    return 1.f / (1.f + __expf(-x));
}

__global__ __launch_bounds__(128)
void tcn_setup(const float* __restrict__ pw_in, const float* __restrict__ gn_g,
               const float* __restrict__ gn_b, float* __restrict__ ws) {
    int i = blockIdx.x;      // layer
    int tid = threadIdx.x;   // 128 threads
    float* WgT = ws + WS_WGT;
    float* Pb  = ws + WS_PB;
    float* Pg  = ws + WS_PG;
    float* Gp  = ws + WS_GP;
    float* Bp  = ws + WS_BP;

    float g = (i == 0) ? 1.f : gn_g[(i - 1) * HC + tid];
    float bb = (i == 0) ? 0.f : gn_b[(i - 1) * HC + tid];
    Gp[i * HC + tid] = g;
    Bp[i * HC + tid] = bb;
    for (int o = 0; o < HB; o++)
        WgT[(i * HC + tid) * HB + o] = pw_in[((size_t)i * HB + o) * HC + tid] * g;

    if (tid < HB) {
        float pb = 0.f, pg = 0.f;
        for (int c = 0; c < HC; c++) {
            float w = pw_in[((size_t)i * HB + tid) * HC + c];
            float gc = (i == 0) ? 1.f : gn_g[(i - 1) * HC + c];
            float bc = (i == 0) ? 0.f : gn_b[(i - 1) * HC + c];
            pb += bc * w;
            pg += gc * w;
        }
        Pb[i * HB + tid] = pb;
        Pg[i * HB + tid] = pg;
    }
}

// Static LDS: halo[64][68] fp32 + sLast[8][128] + small bufs = 22.8 KB
__global__ __launch_bounds__(256, 2)
void tcn_main(const float* __restrict__ x, const float* __restrict__ in_w,
              const float* __restrict__ in_b, const float* __restrict__ dw_w,
              const float* __restrict__ pw_out, const float* __restrict__ skip_w,
              const float* __restrict__ ln_g, const float* __restrict__ ln_b,
              const float* __restrict__ h1_w, const float* __restrict__ h1_b,
              const float* __restrict__ h2_w, const float* __restrict__ h2_b,
              const float* __restrict__ ws, float* __restrict__ out) {
    __shared__ float halo[64 * 68];
    __shared__ float sLast[NL * HC];
    __shared__ float red[16];
    __shared__ float wbuf[64];
    __shared__ float hbuf[128];
    __shared__ float qbuf[128];

    const float* WgT = ws + WS_WGT;
    const float* Pb  = ws + WS_PB;
    const float* Pg  = ws + WS_PG;
    const float* Gp  = ws + WS_GP;
    const float* Bp  = ws + WS_BP;

    const int t = threadIdx.x;     // time index, 0..255
    const int bn = blockIdx.x;     // sample
    const int b = bn >> 7, n = bn & 127;
    const int lane = t & 63;
    const int wv = t >> 6;

    // residual state z[:, t] lives in this thread's registers, fp16-packed:
    // z2[i] = (ch 2i, ch 2i+1)  -> 64 VGPRs instead of 128
    __half2 z2[HC / 2];

    // ---------- phase 0: input projection  z[c] = x[b,t,n,:] @ in_w + in_b
    {
        const float* xp = x + (((size_t)b * TT + t) * 128 + n) * 16;
        float xr[16];
#pragma unroll
        for (int d = 0; d < 16; d++) xr[d] = xp[d];
#pragma unroll
        for (int c = 0; c < HC; c += 2) {
            float a0 = in_b[c], a1 = in_b[c + 1];
#pragma unroll
            for (int d = 0; d < 16; d++) {
                a0 = fmaf(xr[d], in_w[d * HC + c], a0);
                a1 = fmaf(xr[d], in_w[d * HC + c + 1], a1);
            }
            z2[c >> 1] = __floats2half2_rn(a0, a1);
        }
    }

    float m_s = 0.f, r_s = 1.f;   // deferred groupnorm scalars

#pragma unroll 1
    for (int L = 0; L < NL; L++) {
        const int dil = 1 << (L & 3);
        const bool lastL = (L == NL - 1);
        const bool active = (!lastL) || (wv == 3);

        // ---------- u-phase: u[o] = r*(z . WgT[:,o]) + Pb[o] - m*r*Pg[o]
        float u[HB];
        if (active) {
            const float* W = WgT + (size_t)L * HC * HB;
#pragma unroll
            for (int o = 0; o < HB; o++) u[o] = 0.f;
#pragma unroll
            for (int cp = 0; cp < HC / 2; cp++) {
                float z0 = __low2float(z2[cp]);
                float z1 = __high2float(z2[cp]);
#pragma unroll
                for (int o = 0; o < HB; o++) {
                    u[o] = fmaf(z0, W[(2 * cp) * HB + o], u[o]);
                    u[o] = fmaf(z1, W[(2 * cp + 1) * HB + o], u[o]);
                }
            }
            float mr = m_s * r_s;
#pragma unroll
            for (int o = 0; o < HB; o++)
                u[o] = fmaf(r_s, u[o], Pb[L * HB + o] - mr * Pg[L * HB + o]);
            // halo publish: rows with (t&63)>=48 feed next wave's lookback
            if (lane >= 48) {
                int hr = wv * 16 + (lane - 48);
#pragma unroll
                for (int o = 0; o < HB; o++) halo[hr * 68 + o] = u[o];
            }
        }
        __syncthreads();   // B1: halo ready

        // ---------- conv + gating (verified channel mapping)
        // f[c] uses u[c>>1]; gate[c] uses u[32+(c>>1)]
        float w_[HB];
        if (active) {
            const float* dwl = dw_w + (size_t)L * 128 * 3;
            const int d1 = dil, d2 = 2 * dil;
#pragma unroll
            for (int k = 0; k < 32; k++) {
                float uf = u[k];
                float um1 = __shfl_up(uf, d1);
                float um2 = __shfl_up(uf, d2);
                if (lane < d1) {
                    int tau = t - d1;
                    um1 = (tau < 0) ? 0.f : halo[((tau >> 6) * 16 + (tau & 63) - 48) * 68 + k];
                }
                if (lane < d2) {
                    int tau = t - d2;
                    um2 = (tau < 0) ? 0.f : halo[((tau >> 6) * 16 + (tau & 63) - 48) * 68 + k];
                }
                float f0 = um2 * dwl[(2 * k) * 3 + 0] + um1 * dwl[(2 * k) * 3 + 1] + uf * dwl[(2 * k) * 3 + 2];
                float f1 = um2 * dwl[(2 * k + 1) * 3 + 0] + um1 * dwl[(2 * k + 1) * 3 + 1] + uf * dwl[(2 * k + 1) * 3 + 2];
                w_[2 * k] = fast_tanh(f0);
                w_[2 * k + 1] = fast_tanh(f1);
            }
#pragma unroll
            for (int k = 0; k < 32; k++) {
                float ug = u[32 + k];
                float um1 = __shfl_up(ug, d1);
                float um2 = __shfl_up(ug, d2);
                if (lane < d1) {
                    int tau = t - d1;
                    um1 = (tau < 0) ? 0.f : halo[((tau >> 6) * 16 + (tau & 63) - 48) * 68 + 32 + k];
                }
                if (lane < d2) {
                    int tau = t - d2;
                    um2 = (tau < 0) ? 0.f : halo[((tau >> 6) * 16 + (tau & 63) - 48) * 68 + 32 + k];
                }
                float g0 = um2 * dwl[(64 + 2 * k) * 3 + 0] + um1 * dwl[(64 + 2 * k) * 3 + 1] + ug * dwl[(64 + 2 * k) * 3 + 2];
                float g1 = um2 * dwl[(64 + 2 * k + 1) * 3 + 0] + um1 * dwl[(64 + 2 * k + 1) * 3 + 1] + ug * dwl[(64 + 2 * k + 1) * 3 + 2];
                w_[2 * k] *= fast_sig(g0);
                w_[2 * k + 1] *= fast_sig(g1);
            }
        }

        if (!lastL) {
            // ---------- s-phase: s_feat, residual update (deferred GN), stats
            float s1 = 0.f, s2 = 0.f;
            const float* Po = pw_out + (size_t)L * HC * HB;
            const float mr = m_s * r_s;
            const float* gp = Gp + L * HC;
            const float* bp = Bp + L * HC;
#pragma unroll
            for (int c = 0; c < HC; c += 2) {
                float a0 = 0.f, b0 = 0.f, a1 = 0.f, b1 = 0.f;
#pragma unroll
                for (int cc = 0; cc < 32; cc++) {
                    a0 = fmaf(w_[2 * cc],     Po[c * HB + 2 * cc],           a0);
                    b0 = fmaf(w_[2 * cc + 1], Po[c * HB + 2 * cc + 1],       b0);
                    a1 = fmaf(w_[2 * cc],     Po[(c + 1) * HB + 2 * cc],     a1);
                    b1 = fmaf(w_[2 * cc + 1], Po[(c + 1) * HB + 2 * cc + 1], b1);
                }
                float acc0 = a0 + b0, acc1 = a1 + b1;
                if (t == TT - 1) {
                    sLast[L * HC + c] = acc0;
                    sLast[L * HC + c + 1] = acc1;
                }
                float zo0 = __low2float(z2[c >> 1]);
                float zo1 = __high2float(z2[c >> 1]);
                float g0 = gp[c], g1 = gp[c + 1];
                float zn0 = fmaf(zo0, r_s * g0, (bp[c]     - mr * g0) + acc0);
                float zn1 = fmaf(zo1, r_s * g1, (bp[c + 1] - mr * g1) + acc1);
                z2[c >> 1] = __floats2half2_rn(zn0, zn1);
                s1 += zn0 + zn1;
                s2 += zn0 * zn0 + zn1 * zn1;
            }
#pragma unroll
            for (int off = 32; off; off >>= 1) {
                s1 += __shfl_xor(s1, off);
                s2 += __shfl_xor(s2, off);
            }
            if (lane == 0) { red[wv * 2] = s1; red[wv * 2 + 1] = s2; }
            __syncthreads();   // B2
            float S1 = red[0] + red[2] + red[4] + red[6];
            float S2 = red[1] + red[3] + red[5] + red[7];
            float mu = S1 * (1.f / 32768.f);
            float var = S2 * (1.f / 32768.f) - mu * mu;
            m_s = mu;
            r_s = rsqrtf(var + 1e-5f);
        } else {
            // last layer: only t==255's gated output matters; parallelize its s-row
            if (t == TT - 1) {
#pragma unroll
                for (int cc = 0; cc < HB; cc++) wbuf[cc] = w_[cc];
            }
            __syncthreads();   // B2: wbuf ready
            if (t < HC) {
                const float* pr = pw_out + ((size_t)(NL - 1) * HC + t) * HB;
                float a = 0.f;
                for (int cc = 0; cc < HB; cc++) a = fmaf(wbuf[cc], pr[cc], a);
                sLast[(NL - 1) * HC + t] = a;
            }
            __syncthreads();   // B3: sLast complete
        }
    }

    // ---------- head: h_last = sum_i skip_w[i] @ sLast[i]; LN; MLP
    float hl = 0.f;
    if (t < HC) {
        for (int i = 0; i < NL; i++) {
            const float4* swr = (const float4*)(skip_w + (((size_t)i * HC) + t) * HC);
            const float* sl = sLast + i * HC;
#pragma unroll 4
            for (int c4 = 0; c4 < 32; c4++) {
                float4 sw = swr[c4];
                hl += sw.x * sl[4 * c4] + sw.y * sl[4 * c4 + 1] + sw.z * sl[4 * c4 + 2] + sw.w * sl[4 * c4 + 3];
            }
        }
        hbuf[t] = hl;
    }
    __syncthreads();
    if (t < 64) {
        float v0 = hbuf[t], v1 = hbuf[t + 64];
        float a = v0 + v1, q = v0 * v0 + v1 * v1;
#pragma unroll
        for (int off = 32; off; off >>= 1) {
            a += __shfl_xor(a, off);
            q += __shfl_xor(q, off);
        }
        if (t == 0) {
            float mu = a * (1.f / 128.f);
            red[0] = mu;
            red[1] = rsqrtf(q * (1.f / 128.f) - mu * mu + 1e-5f);
        }
    }
    __syncthreads();
    {
        float mu = red[0], rs = red[1];
        if (t < HC) hbuf[t] = (hl - mu) * rs * ln_g[t] + ln_b[t];
    }
    __syncthreads();
    if (t < HC) {
        float q = h1_b[t];
        for (int c = 0; c < HC; c++) q = fmaf(hbuf[c], h1_w[c * HC + t], q);
        q = 0.5f * q * (1.f + erff(q * 0.70710678118654752f));
        qbuf[t] = q;
    }
    __syncthreads();
    if (t < 24) {
        float o = h2_b[t];
        for (int c = 0; c < HC; c++) o = fmaf(qbuf[c], h2_w[c * 24 + t], o);
        out[((size_t)b * 24 + t) * 128 + n] = o;
    }
}

extern "C" void kernel_launch(void* const* d_in, const int* in_sizes, int n_in,
                              void* d_out, int out_size, void* d_ws, size_t ws_size,
                              hipStream_t stream) {
    const float* x      = (const float*)d_in[0];
    const float* in_w   = (const float*)d_in[1];
    const float* in_b   = (const float*)d_in[2];
    const float* pw_in  = (const float*)d_in[3];
    const float* dw_w   = (const float*)d_in[4];
    const float* pw_out = (const float*)d_in[5];
    const float* gn_g   = (const float*)d_in[6];
    const float* gn_b   = (const float*)d_in[7];
    const float* skip_w = (const float*)d_in[8];
    const float* ln_g   = (const float*)d_in[9];
    const float* ln_b   = (const float*)d_in[10];
    const float* h1_w   = (const float*)d_in[11];
    const float* h1_b   = (const float*)d_in[12];
    const float* h2_w   = (const float*)d_in[13];
    const float* h2_b   = (const float*)d_in[14];
    float* out = (float*)d_out;
    float* ws  = (float*)d_ws;

    tcn_setup<<<NL, 128, 0, stream>>>(pw_in, gn_g, gn_b, ws);

    tcn_main<<<1024, 256, 0, stream>>>(x, in_w, in_b, dw_w, pw_out, skip_w,
                                       ln_g, ln_b, h1_w, h1_b, h2_w, h2_b, ws, out);
}